// Round 5
// baseline (1011.049 us; speedup 1.0000x reference)
//
#include <hip/hip_runtime.h>
#include <cstdint>

typedef unsigned short u16;
typedef unsigned int u32;

#define N_TOKENS 8192
#define D_MODEL 1024
#define DIM_FF 4096
#define N_EXPERTS 8
#define MAX_SLOTS (N_TOKENS * 2)

typedef __bf16 bf16x8 __attribute__((ext_vector_type(8)));
typedef float f32x4 __attribute__((ext_vector_type(4)));

// ---------- helpers ----------
__device__ __forceinline__ u16 f2bf(float f) {
  u32 u = __float_as_uint(f);
  u32 r = (u + 0x7FFFu + ((u >> 16) & 1u)) >> 16;  // RNE
  return (u16)r;
}
__device__ __forceinline__ u16 bfc(float f) {
  __bf16 b = (__bf16)f;
  return __builtin_bit_cast(u16, b);
}

// async global->LDS, 16B per lane; LDS dst = wave-uniform base + lane*16
__device__ __forceinline__ void gl2lds16(const void* g, void* l) {
  __builtin_amdgcn_global_load_lds(
      (__attribute__((address_space(1))) void*)(g),
      (__attribute__((address_space(3))) void*)(l), 16, 0, 0);
}

__device__ __forceinline__ u32 lds_addr(const void* p) {
  return (u32)(uintptr_t)(__attribute__((address_space(3))) const void*)p;
}

__device__ __forceinline__ bf16x8 dsr128(u32 addr) {
  bf16x8 r;
  asm volatile("ds_read_b128 %0, %1" : "=v"(r) : "v"(addr));
  return r;
}

#define BARX() asm volatile("s_barrier" ::: "memory")
#define LGKM0() do { asm volatile("s_waitcnt lgkmcnt(0)" ::: "memory"); __builtin_amdgcn_sched_barrier(0); } while (0)
#define VMC(n) asm volatile("s_waitcnt vmcnt(" #n ")" ::: "memory")

// ---------- gate (+ fused x->bf16 cvt) ----------
__global__ __launch_bounds__(256) void gate_kernel(
    const float* __restrict__ x, const float* __restrict__ Wg,
    const float* __restrict__ bg, int* __restrict__ eidx,
    float* __restrict__ ew, u16* __restrict__ xb) {
  int tok = (int)((blockIdx.x * 256 + threadIdx.x) >> 6);
  int lane = threadIdx.x & 63;
  const float* xr = x + (size_t)tok * D_MODEL;
  u16* xbr = xb + (size_t)tok * D_MODEL;
  float acc[8] = {0.f, 0.f, 0.f, 0.f, 0.f, 0.f, 0.f, 0.f};
#pragma unroll
  for (int j = 0; j < 8; ++j) {
    int d = 2 * lane + 128 * j;
    float2 xv = *(const float2*)(xr + d);
    float4 wa0 = *(const float4*)(Wg + d * 8);
    float4 wb0 = *(const float4*)(Wg + d * 8 + 4);
    float4 wa1 = *(const float4*)(Wg + d * 8 + 8);
    float4 wb1 = *(const float4*)(Wg + d * 8 + 12);
    acc[0] += xv.x * wa0.x + xv.y * wa1.x;
    acc[1] += xv.x * wa0.y + xv.y * wa1.y;
    acc[2] += xv.x * wa0.z + xv.y * wa1.z;
    acc[3] += xv.x * wa0.w + xv.y * wa1.w;
    acc[4] += xv.x * wb0.x + xv.y * wb1.x;
    acc[5] += xv.x * wb0.y + xv.y * wb1.y;
    acc[6] += xv.x * wb0.z + xv.y * wb1.z;
    acc[7] += xv.x * wb0.w + xv.y * wb1.w;
    u32 pk = (u32)f2bf(xv.x) | ((u32)f2bf(xv.y) << 16);
    *(u32*)(xbr + d) = pk;
  }
#pragma unroll
  for (int off = 32; off > 0; off >>= 1) {
#pragma unroll
    for (int e = 0; e < 8; ++e) acc[e] += __shfl_xor(acc[e], off, 64);
  }
  if (lane == 0) {
    float p[8], m = -1e30f;
#pragma unroll
    for (int e = 0; e < 8; ++e) { p[e] = acc[e] + bg[e]; m = fmaxf(m, p[e]); }
    float s = 0.f;
#pragma unroll
    for (int e = 0; e < 8; ++e) { p[e] = __expf(p[e] - m); s += p[e]; }
#pragma unroll
    for (int e = 0; e < 8; ++e) p[e] /= s;
    int i0 = 0;
#pragma unroll
    for (int e = 1; e < 8; ++e) if (p[e] > p[i0]) i0 = e;
    int i1 = (i0 == 0) ? 1 : 0;
#pragma unroll
    for (int e = 0; e < 8; ++e) if (e != i0 && p[e] > p[i1]) i1 = e;
    float denom = p[i0] + p[i1] + 1e-9f;
    eidx[2 * tok] = i0; eidx[2 * tok + 1] = i1;
    ew[2 * tok] = p[i0] / denom; ew[2 * tok + 1] = p[i1] / denom;
  }
}

// ---------- count ----------
__global__ __launch_bounds__(256) void count_kernel(const int* __restrict__ eidx,
                                                    int* __restrict__ counts) {
  __shared__ int lc[16];
  int tid = threadIdx.x;
  if (tid < 16) lc[tid] = 0;
  __syncthreads();
  int t = blockIdx.x * 256 + tid;
  atomicAdd(&lc[2 * eidx[2 * t]], 1);
  atomicAdd(&lc[2 * eidx[2 * t + 1] + 1], 1);
  __syncthreads();
  if (tid < 16) atomicAdd(&counts[tid], lc[tid]);
}

// ---------- fill (+ tileMap build for 256-row slot tiles) ----------
__global__ __launch_bounds__(256) void fill_kernel(
    const int* __restrict__ eidx, const float* __restrict__ ew,
    const int* __restrict__ counts, int* __restrict__ fill,
    int* __restrict__ rowtok, float* __restrict__ rowwt,
    int* __restrict__ tmap) {
  __shared__ int lc[16];
  __shared__ int lbase[16];
  __shared__ int loff[16];
  int tid = threadIdx.x;
  if (tid < 16) lc[tid] = 0;
  __syncthreads();
  int t = blockIdx.x * 256 + tid;
  int e0 = eidx[2 * t], e1 = eidx[2 * t + 1];
  int p0 = atomicAdd(&lc[2 * e0], 1);
  int p1 = atomicAdd(&lc[2 * e1 + 1], 1);
  __syncthreads();
  if (tid < 16) lbase[tid] = atomicAdd(&fill[tid], lc[tid]);
  if (tid == 64) {
    int o = 0;
    for (int g = 0; g < 16; ++g) { loff[g] = o; o += counts[g]; }
  }
  if (blockIdx.x == 0 && tid == 128) {
    // tmap[0] = ntiles; entries: (expert<<16)|rtile. Sum ceil(cnt_e/256) <= 71.
    int nt2 = 0;
    for (int ee = 0; ee < N_EXPERTS; ++ee) {
      int c = counts[2 * ee] + counts[2 * ee + 1];
      int ntile = (c + 255) >> 8;
      for (int r = 0; r < ntile; ++r) tmap[1 + nt2++] = (ee << 16) | r;
    }
    tmap[0] = nt2;
  }
  __syncthreads();
  int pos0 = loff[2 * e0] + lbase[2 * e0] + p0;
  int pos1 = loff[2 * e1 + 1] + lbase[2 * e1 + 1] + p1;
  rowtok[pos0] = t; rowwt[pos0] = ew[2 * t];
  rowtok[pos1] = t; rowwt[pos1] = ew[2 * t + 1];
}

// ---------- per-expert transpose+convert: in [R][C] fp32 -> out [C][R] bf16 ----------
__global__ __launch_bounds__(256) void transpose_cvt(const float* __restrict__ in,
                                                     u16* __restrict__ out, int R, int C) {
  int e = blockIdx.z;
  const float* ip = in + (size_t)e * R * C;
  u16* op = out + (size_t)e * R * C;
  int c0 = blockIdx.x * 64, r0 = blockIdx.y * 64;
  __shared__ __align__(16) u16 t[64 * 68];
  int tid = threadIdx.x;
  int c4 = (tid & 15) * 4;
#pragma unroll
  for (int p = 0; p < 4; ++p) {
    int r = (tid >> 4) + 16 * p;
    float4 v = *(const float4*)(ip + (size_t)(r0 + r) * C + c0 + c4);
    uint2 pk;
    pk.x = (u32)bfc(v.x) | ((u32)bfc(v.y) << 16);
    pk.y = (u32)bfc(v.z) | ((u32)bfc(v.w) << 16);
    *(uint2*)&t[r * 68 + c4] = pk;
  }
  __syncthreads();
  int pair = tid >> 3;
  int r8 = (tid & 7) * 8;
  int c = 2 * pair;
  u32 u[8];
#pragma unroll
  for (int j = 0; j < 8; ++j) u[j] = *(const u32*)&t[(r8 + j) * 68 + c];
  uint4 lo, hi;
  lo.x = (u[0] & 0xffffu) | (u[1] << 16);
  lo.y = (u[2] & 0xffffu) | (u[3] << 16);
  lo.z = (u[4] & 0xffffu) | (u[5] << 16);
  lo.w = (u[6] & 0xffffu) | (u[7] << 16);
  hi.x = (u[0] >> 16) | (u[1] & 0xffff0000u);
  hi.y = (u[2] >> 16) | (u[3] & 0xffff0000u);
  hi.z = (u[4] >> 16) | (u[5] & 0xffff0000u);
  hi.w = (u[6] >> 16) | (u[7] & 0xffff0000u);
  *(uint4*)(op + (size_t)(c0 + c) * R + r0 + r8) = lo;
  *(uint4*)(op + (size_t)(c0 + c + 1) * R + r0 + r8) = hi;
}

// ======================================================================
// 256x256 8-phase GEMM core, CORRECTED STAGGER (R3 failure = A-prefetch
// cover of only 2 phases + miscounted vmcnt):
//  - each stage is issued the phase AFTER its LDS region is last consumed
//    (buf-B frees at ph2/ph6, buf-A at ph3/ph7) -> 4-6 phases of cover
//  - wait points count the queue exactly: 16 outstanding -> vmcnt(8)
//    drains precisely the previous K-tile's 8 loads; never 0 mid-loop.
//  Geometry identical to R3 (correctness-validated): BK=64, 512 thr,
//  dbuf 128 KiB, both-sides (row&7) XOR swizzle, zero bank conflicts.
// ======================================================================

#define STG_A(buf, h, ktv) do { \
  gl2lds16(aS##h##0 + (size_t)(ktv) * 64, lds + (buf) * 32768 + (h) * 16384 + 0 + tid * 16); \
  gl2lds16(aS##h##1 + (size_t)(ktv) * 64, lds + (buf) * 32768 + (h) * 16384 + 8192 + tid * 16); \
} while (0)
#define STG_B(buf, h, ktv) do { \
  gl2lds16(bS##h##0 + (size_t)(ktv) * 64, lds + 65536 + (buf) * 32768 + (h) * 16384 + 0 + tid * 16); \
  gl2lds16(bS##h##1 + (size_t)(ktv) * 64, lds + 65536 + (buf) * 32768 + (h) * 16384 + 8192 + tid * 16); \
} while (0)

#define RDA(DST, BO, QO) do { \
  _Pragma("unroll") \
  for (int mi_ = 0; mi_ < 4; ++mi_) { \
    DST[mi_][0] = dsr128(aR0 + (BO) + (QO) + mi_ * 2048); \
    DST[mi_][1] = dsr128(aR1 + (BO) + (QO) + mi_ * 2048); \
  } \
} while (0)
#define RDB(DST, BO, HO) do { \
  _Pragma("unroll") \
  for (int ni_ = 0; ni_ < 2; ++ni_) { \
    DST[ni_][0] = dsr128(bR0 + (BO) + (HO) + ni_ * 2048); \
    DST[ni_][1] = dsr128(bR1 + (BO) + (HO) + ni_ * 2048); \
  } \
} while (0)

#define QMM(MO, NO, AF, BF) do { \
  __builtin_amdgcn_s_setprio(1); \
  _Pragma("unroll") \
  for (int mi_ = 0; mi_ < 4; ++mi_) \
    _Pragma("unroll") \
    for (int ni_ = 0; ni_ < 2; ++ni_) \
      _Pragma("unroll") \
      for (int ks_ = 0; ks_ < 2; ++ks_) \
        acc[(MO) + mi_][(NO) + ni_] = __builtin_amdgcn_mfma_f32_16x16x32_bf16( \
            AF[mi_][ks_], BF[ni_][ks_], acc[(MO) + mi_][(NO) + ni_], 0, 0, 0); \
  __builtin_amdgcn_s_setprio(0); \
} while (0)

// one iteration = 2 K-tiles (buf0 then buf1), 8 phases.
// steady state entering ph0: outstanding = {B(kt+1),A(kt+1)} = 8 loads.
#define KITER(KT, NL) do { \
  /* ph0: buf0 Q00 */ \
  RDA(af, 0, 0); RDB(bl, 0, 0); \
  BARX(); LGKM0(); \
  QMM(0, 0, af, bl); \
  BARX(); \
  /* ph1: buf0 Q01 */ \
  RDB(bh, 0, 4096); \
  BARX(); LGKM0(); \
  QMM(0, 2, af, bh); \
  BARX(); \
  /* ph2: buf0-B consumed -> prefetch B(kt+2) into buf0 */ \
  RDA(ah, 0, 8192); \
  if (NL) { STG_B(0, 0, (KT) + 2); STG_B(0, 1, (KT) + 2); } \
  BARX(); LGKM0(); \
  QMM(4, 0, ah, bl); \
  BARX(); \
  /* ph3: buf0-A consumed -> prefetch A(kt+2); wait buf1(kt+1) landed */ \
  if (NL) { STG_A(0, 0, (KT) + 2); STG_A(0, 1, (KT) + 2); VMC(8); } else { VMC(0); } \
  BARX(); \
  QMM(4, 2, ah, bh); \
  BARX(); \
  /* ph4: buf1 Q00 */ \
  RDA(af, 32768, 0); RDB(bl, 32768, 0); \
  BARX(); LGKM0(); \
  QMM(0, 0, af, bl); \
  BARX(); \
  /* ph5: buf1 Q01 */ \
  RDB(bh, 32768, 4096); \
  BARX(); LGKM0(); \
  QMM(0, 2, af, bh); \
  BARX(); \
  /* ph6: buf1-B consumed -> prefetch B(kt+3) into buf1 */ \
  RDA(ah, 32768, 8192); \
  if (NL) { STG_B(1, 0, (KT) + 3); STG_B(1, 1, (KT) + 3); } \
  BARX(); LGKM0(); \
  QMM(4, 0, ah, bl); \
  BARX(); \
  /* ph7: buf1-A consumed -> prefetch A(kt+3); wait buf0(kt+2) landed */ \
  if (NL) { STG_A(1, 0, (KT) + 3); STG_A(1, 1, (KT) + 3); VMC(8); } \
  BARX(); \
  QMM(4, 2, ah, bh); \
  BARX(); \
} while (0)

// ---------- fc1: H[slot,f] = gelu(Xg @ W1 + b1), bf16, 256^2 8-phase ----------
__global__ __launch_bounds__(512) void fc1_kernel(
    const u16* __restrict__ xb, const u16* __restrict__ w1t,
    const float* __restrict__ b1, const int* __restrict__ rowtok,
    const int* __restrict__ counts, const int* __restrict__ tmap,
    u16* __restrict__ H) {
  // XCD-contiguous swizzle: nwg=1152=8*144; all 16 ct-blocks of a slot tile
  // land on ONE XCD -> A-panel (2 MB) L2-resident per XCD.
  const int bx0 = blockIdx.x;
  const int bx = (bx0 & 7) * 144 + (bx0 >> 3);
  const int t = bx >> 4;     // slot tile
  const int ct = bx & 15;    // 256-col tile of DIM_FF
  if (t >= tmap[0]) return;
  const int ent = tmap[1 + t];
  const int e = ent >> 16;
  const int rt = ent & 0xffff;
  int base = 0;
#pragma unroll
  for (int g = 0; g < 16; ++g) base += (g < 2 * e) ? counts[g] : 0;
  const int count = counts[2 * e] + counts[2 * e + 1];

  extern __shared__ char lds[];
  const int tid = threadIdx.x;

  // staging sources (A gathered via rowtok, clamped; B = w1t rows)
  const int sub = tid >> 3;
  const int csrc = (tid & 7) ^ (sub & 7);
  const int lastslot = base + count - 1;
  const u16* wb = w1t + (size_t)e * ((size_t)DIM_FF * D_MODEL);
  int s00 = base + rt * 256 + 0 + sub;   if (s00 > lastslot) s00 = lastslot;
  int s01 = base + rt * 256 + 64 + sub;  if (s01 > lastslot) s01 = lastslot;
  int s10 = base + rt * 256 + 128 + sub; if (s10 > lastslot) s10 = lastslot;
  int s11 = base + rt * 256 + 192 + sub; if (s11 > lastslot) s11 = lastslot;
  const u16* aS00 = xb + (size_t)rowtok[s00] * D_MODEL + csrc * 8;
  const u16* aS01 = xb + (size_t)rowtok[s01] * D_MODEL + csrc * 8;
  const u16* aS10 = xb + (size_t)rowtok[s10] * D_MODEL + csrc * 8;
  const u16* aS11 = xb + (size_t)rowtok[s11] * D_MODEL + csrc * 8;
  const u16* bS00 = wb + (size_t)(ct * 256 + 0 + sub) * D_MODEL + csrc * 8;
  const u16* bS01 = wb + (size_t)(ct * 256 + 64 + sub) * D_MODEL + csrc * 8;
  const u16* bS10 = wb + (size_t)(ct * 256 + 128 + sub) * D_MODEL + csrc * 8;
  const u16* bS11 = wb + (size_t)(ct * 256 + 192 + sub) * D_MODEL + csrc * 8;

  // read-side swizzled bases
  const int lane = tid & 63, wid = tid >> 6;
  const int wm = wid & 1, wn = wid >> 1;
  const int lc = lane & 15, quad = lane >> 4;
  const u32 lb = lds_addr(lds);
  const u32 aR0 = lb + (u32)((wm * 128 + lc) * 128 + (((0 + quad) ^ (lc & 7)) * 16));
  const u32 aR1 = lb + (u32)((wm * 128 + lc) * 128 + (((4 + quad) ^ (lc & 7)) * 16));
  const u32 bR0 = lb + 65536u + (u32)((wn * 64 + lc) * 128 + (((0 + quad) ^ (lc & 7)) * 16));
  const u32 bR1 = lb + 65536u + (u32)((wn * 64 + lc) * 128 + (((4 + quad) ^ (lc & 7)) * 16));

  f32x4 acc[8][4];
#pragma unroll
  for (int i = 0; i < 8; ++i)
#pragma unroll
    for (int j = 0; j < 4; ++j) acc[i][j] = (f32x4)0.0f;
  bf16x8 af[4][2], ah[4][2], bl[2][2], bh[2][2];

  // prologue: all 4 half-panels; vmcnt(8) = buf0 complete (steady-state inv.)
  STG_B(0, 0, 0); STG_B(0, 1, 0); STG_A(0, 0, 0); STG_A(0, 1, 0);
  STG_B(1, 0, 1); STG_B(1, 1, 1); STG_A(1, 0, 1); STG_A(1, 1, 1);
  VMC(8); BARX();

  const int NITER = (D_MODEL / 64) / 2;  // 8
  for (int it = 0; it < NITER; ++it) {
    const int kt = 2 * it;
    const bool nl = (it < NITER - 1);
    KITER(kt, nl);
  }

  // epilogue: bias + GELU -> bf16 H
  float bias[4];
#pragma unroll
  for (int ni = 0; ni < 4; ++ni) bias[ni] = b1[e * DIM_FF + ct * 256 + wn * 64 + ni * 16 + lc];
#pragma unroll
  for (int mi = 0; mi < 8; ++mi) {
#pragma unroll
    for (int r = 0; r < 4; ++r) {
      int grow = rt * 256 + wm * 128 + mi * 16 + quad * 4 + r;
      if (grow < count) {
        size_t rowbase = (size_t)(base + grow) * DIM_FF + ct * 256 + wn * 64;
#pragma unroll
        for (int ni = 0; ni < 4; ++ni) {
          float v = acc[mi][ni][r] + bias[ni];
          float t3 = v * (1.0f + 0.044715f * v * v);
          float u = __builtin_amdgcn_exp2f(fminf(2.302208f * t3, 80.0f));
          float h = v * u * __builtin_amdgcn_rcpf(u + 1.0f);
          H[rowbase + ni * 16 + lc] = f2bf(h);
        }
      }
    }
  }
}

// ---------- fc2: out[tok] += wt*(H @ W2 + b2), merged top1+2, ks-split x2 ----------
__global__ __launch_bounds__(512) void fc2_kernel(
    const u16* __restrict__ H, const u16* __restrict__ w2t,
    const float* __restrict__ b2, const int* __restrict__ rowtok,
    const float* __restrict__ rowwt, const int* __restrict__ counts,
    const int* __restrict__ tmap, float* __restrict__ out) {
  // XCD-contiguous swizzle: nwg=576=8*72; all 8 (ct,ks)-blocks of a slot
  // tile on one XCD -> H-panel L2-resident.
  const int bx0 = blockIdx.x;
  const int bx = (bx0 & 7) * 72 + (bx0 >> 3);
  const int t = bx >> 3;
  const int c8 = bx & 7;
  const int ct = c8 >> 1;   // 0..3 (256-col tile of D_MODEL)
  const int ks = c8 & 1;    // K half
  if (t >= tmap[0]) return;
  const int ent = tmap[1 + t];
  const int e = ent >> 16;
  const int rt = ent & 0xffff;
  int base = 0;
#pragma unroll
  for (int g = 0; g < 16; ++g) base += (g < 2 * e) ? counts[g] : 0;
  const int count = counts[2 * e] + counts[2 * e + 1];

  extern __shared__ char lds[];
  const int tid = threadIdx.x;

  const int sub = tid >> 3;
  const int csrc = (tid & 7) ^ (sub & 7);
  const u16* hb = H + (size_t)(base + rt * 256) * DIM_FF + (size_t)ks * (DIM_FF / 2) + csrc * 8;
  const u16* aS00 = hb + (size_t)(0 + sub) * DIM_FF;
  const u16* aS01 = hb + (size_t)(64 + sub) * DIM_FF;
  const u16* aS10 = hb + (size_t)(128 + sub) * DIM_FF;
  const u16* aS11 = hb + (size_t)(192 + sub) * DIM_FF;
  const u16* wb = w2t + (size_t)e * ((size_t)D_MODEL * DIM_FF) + (size_t)ks * (DIM_FF / 2) + csrc * 8;
  const u16* bS00 = wb + (size_t)(ct * 256 + 0 + sub) * DIM_FF;
  const u16* bS01 = wb + (size_t)(ct * 256 + 64 + sub) * DIM_FF;
  const u16* bS10 = wb + (size_t)(ct * 256 + 128 + sub) * DIM_FF;
  const u16* bS11 = wb + (size_t)(ct * 256 + 192 + sub) * DIM_FF;

  const int lane = tid & 63, wid = tid >> 6;
  const int wm = wid & 1, wn = wid >> 1;
  const int lc = lane & 15, quad = lane >> 4;
  const u32 lb = lds_addr(lds);
  const u32 aR0 = lb + (u32)((wm * 128 + lc) * 128 + (((0 + quad) ^ (lc & 7)) * 16));
  const u32 aR1 = lb + (u32)((wm * 128 + lc) * 128 + (((4 + quad) ^ (lc & 7)) * 16));
  const u32 bR0 = lb + 65536u + (u32)((wn * 64 + lc) * 128 + (((0 + quad) ^ (lc & 7)) * 16));
  const u32 bR1 = lb + 65536u + (u32)((wn * 64 + lc) * 128 + (((4 + quad) ^ (lc & 7)) * 16));

  f32x4 acc[8][4];
#pragma unroll
  for (int i = 0; i < 8; ++i)
#pragma unroll
    for (int j = 0; j < 4; ++j) acc[i][j] = (f32x4)0.0f;
  bf16x8 af[4][2], ah[4][2], bl[2][2], bh[2][2];

  STG_B(0, 0, 0); STG_B(0, 1, 0); STG_A(0, 0, 0); STG_A(0, 1, 0);
  STG_B(1, 0, 1); STG_B(1, 1, 1); STG_A(1, 0, 1); STG_A(1, 1, 1);
  VMC(8); BARX();

  const int NITER = ((DIM_FF / 2) / 64) / 2;  // 16
  for (int it = 0; it < NITER; ++it) {
    const int kt = 2 * it;
    const bool nl = (it < NITER - 1);
    KITER(kt, nl);
  }

  float bias[4];
#pragma unroll
  for (int ni = 0; ni < 4; ++ni)
    bias[ni] = (ks == 0) ? b2[e * D_MODEL + ct * 256 + wn * 64 + ni * 16 + lc] : 0.0f;
#pragma unroll
  for (int mi = 0; mi < 8; ++mi) {
#pragma unroll
    for (int r = 0; r < 4; ++r) {
      int grow = rt * 256 + wm * 128 + mi * 16 + quad * 4 + r;
      if (grow < count) {
        int slot = base + grow;
        float wt = rowwt[slot];
        float* orow = out + (size_t)rowtok[slot] * D_MODEL + ct * 256 + wn * 64;
#pragma unroll
        for (int ni = 0; ni < 4; ++ni)
          unsafeAtomicAdd(orow + ni * 16 + lc, wt * (acc[mi][ni][r] + bias[ni]));
      }
    }
  }
}

extern "C" void kernel_launch(void* const* d_in, const int* in_sizes, int n_in,
                              void* d_out, int out_size, void* d_ws, size_t ws_size,
                              hipStream_t stream) {
  (void)in_sizes; (void)n_in; (void)ws_size; (void)out_size;
  const float* x  = (const float*)d_in[0];
  const float* Wg = (const float*)d_in[1];
  const float* bg = (const float*)d_in[2];
  const float* W1 = (const float*)d_in[3];
  const float* b1 = (const float*)d_in[4];
  const float* W2 = (const float*)d_in[5];
  const float* b2 = (const float*)d_in[6];
  float* out = (float*)d_out;

  char* ws = (char*)d_ws;
  size_t off = 0;
  int*   counts  = (int*)(ws + 0);     // 16 ints
  int*   fill    = (int*)(ws + 128);   // 16 ints
  int*   tmap    = (int*)(ws + 256);   // 1 + 72 ints
  off = 4096;
  int*   eidx    = (int*)(ws + off); off += 65536;
  float* ew      = (float*)(ws + off); off += 65536;
  int*   rowtok  = (int*)(ws + off); off += 65536;
  float* rowwt   = (float*)(ws + off); off += 65536;
  u16*   xb      = (u16*)(ws + off); off += (size_t)N_TOKENS * D_MODEL * 2;
  u16*   w1t     = (u16*)(ws + off);
  u16*   w2t     = w1t;  // ALIASED: W2 transposed after fc1 finishes reading w1t
  off += (size_t)N_EXPERTS * DIM_FF * D_MODEL * 2;
  u16*   H       = (u16*)(ws + off);
  off += (size_t)(MAX_SLOTS + 256) * DIM_FF * 2;  // +256 rows: unguarded tail reads

  static int attr_done = 0;
  if (!attr_done) {
    hipFuncSetAttribute((const void*)fc1_kernel, hipFuncAttributeMaxDynamicSharedMemorySize, 131072);
    hipFuncSetAttribute((const void*)fc2_kernel, hipFuncAttributeMaxDynamicSharedMemorySize, 131072);
    attr_done = 1;
  }

  hipMemsetAsync(ws, 0, 4096, stream);
  hipMemsetAsync(out, 0, (size_t)N_TOKENS * D_MODEL * sizeof(float), stream);

  gate_kernel<<<N_TOKENS / 4, 256, 0, stream>>>(x, Wg, bg, eidx, ew, xb);
  count_kernel<<<N_TOKENS / 256, 256, 0, stream>>>(eidx, counts);
  fill_kernel<<<N_TOKENS / 256, 256, 0, stream>>>(eidx, ew, counts, fill, rowtok, rowwt, tmap);
  transpose_cvt<<<dim3(DIM_FF / 64, D_MODEL / 64, N_EXPERTS), 256, 0, stream>>>(W1, w1t, D_MODEL, DIM_FF);
  fc1_kernel<<<72 * 16, 512, 131072, stream>>>(xb, w1t, b1, rowtok, counts, tmap, H);
  transpose_cvt<<<dim3(D_MODEL / 64, DIM_FF / 64, N_EXPERTS), 256, 0, stream>>>(W2, w2t, DIM_FF, D_MODEL);
  fc2_kernel<<<72 * 8, 512, 131072, stream>>>(H, w2t, b2, rowtok, rowwt, counts, tmap, out);
}

// Round 6
// 790.923 us; speedup vs baseline: 1.2783x; 1.2783x over previous
//
#include <hip/hip_runtime.h>
#include <cstdint>

typedef unsigned short u16;
typedef unsigned int u32;

#define N_TOKENS 8192
#define D_MODEL 1024
#define DIM_FF 4096
#define N_EXPERTS 8
#define MAX_SLOTS (N_TOKENS * 2)

typedef __bf16 bf16x8 __attribute__((ext_vector_type(8)));
typedef float f32x4 __attribute__((ext_vector_type(4)));

// ---------- helpers ----------
__device__ __forceinline__ u16 f2bf(float f) {
  u32 u = __float_as_uint(f);
  u32 r = (u + 0x7FFFu + ((u >> 16) & 1u)) >> 16;  // RNE
  return (u16)r;
}
__device__ __forceinline__ u16 bfc(float f) {  // native cvt (RNE), 1 VALU op
  __bf16 b = (__bf16)f;
  return __builtin_bit_cast(u16, b);
}

// async global->LDS, 16B per lane; LDS dst = wave-uniform base + lane*16
__device__ __forceinline__ void gl2lds16(const void* g, void* l) {
  __builtin_amdgcn_global_load_lds(
      (__attribute__((address_space(1))) void*)(g),
      (__attribute__((address_space(3))) void*)(l), 16, 0, 0);
}

// ---------- gate (+ fused x->bf16 cvt): logits -> softmax -> top2 -> renorm ----------
__global__ __launch_bounds__(256) void gate_kernel(
    const float* __restrict__ x, const float* __restrict__ Wg,
    const float* __restrict__ bg, int* __restrict__ eidx,
    float* __restrict__ ew, u16* __restrict__ xb) {
  int tok = (int)((blockIdx.x * 256 + threadIdx.x) >> 6);
  int lane = threadIdx.x & 63;
  const float* xr = x + (size_t)tok * D_MODEL;
  u16* xbr = xb + (size_t)tok * D_MODEL;
  float acc[8] = {0.f, 0.f, 0.f, 0.f, 0.f, 0.f, 0.f, 0.f};
#pragma unroll
  for (int j = 0; j < 8; ++j) {
    int d = 2 * lane + 128 * j;
    float2 xv = *(const float2*)(xr + d);
    float4 wa0 = *(const float4*)(Wg + d * 8);
    float4 wb0 = *(const float4*)(Wg + d * 8 + 4);
    float4 wa1 = *(const float4*)(Wg + d * 8 + 8);
    float4 wb1 = *(const float4*)(Wg + d * 8 + 12);
    acc[0] += xv.x * wa0.x + xv.y * wa1.x;
    acc[1] += xv.x * wa0.y + xv.y * wa1.y;
    acc[2] += xv.x * wa0.z + xv.y * wa1.z;
    acc[3] += xv.x * wa0.w + xv.y * wa1.w;
    acc[4] += xv.x * wb0.x + xv.y * wb1.x;
    acc[5] += xv.x * wb0.y + xv.y * wb1.y;
    acc[6] += xv.x * wb0.z + xv.y * wb1.z;
    acc[7] += xv.x * wb0.w + xv.y * wb1.w;
    u32 pk = (u32)f2bf(xv.x) | ((u32)f2bf(xv.y) << 16);
    *(u32*)(xbr + d) = pk;  // lanes consecutive -> coalesced 256B/wave
  }
#pragma unroll
  for (int off = 32; off > 0; off >>= 1) {
#pragma unroll
    for (int e = 0; e < 8; ++e) acc[e] += __shfl_xor(acc[e], off, 64);
  }
  if (lane == 0) {
    float p[8], m = -1e30f;
#pragma unroll
    for (int e = 0; e < 8; ++e) { p[e] = acc[e] + bg[e]; m = fmaxf(m, p[e]); }
    float s = 0.f;
#pragma unroll
    for (int e = 0; e < 8; ++e) { p[e] = __expf(p[e] - m); s += p[e]; }
#pragma unroll
    for (int e = 0; e < 8; ++e) p[e] /= s;
    int i0 = 0;
#pragma unroll
    for (int e = 1; e < 8; ++e) if (p[e] > p[i0]) i0 = e;
    int i1 = (i0 == 0) ? 1 : 0;
#pragma unroll
    for (int e = 0; e < 8; ++e) if (e != i0 && p[e] > p[i1]) i1 = e;
    float denom = p[i0] + p[i1] + 1e-9f;
    eidx[2 * tok] = i0; eidx[2 * tok + 1] = i1;   // k=0: top-1, k=1: top-2
    ew[2 * tok] = p[i0] / denom; ew[2 * tok + 1] = p[i1] / denom;
  }
}

// ---------- count: per-block LDS histogram over (expert,rank) -> 16 atomics/block ----------
__global__ __launch_bounds__(256) void count_kernel(const int* __restrict__ eidx,
                                                    int* __restrict__ counts) {
  __shared__ int lc[16];
  int tid = threadIdx.x;
  if (tid < 16) lc[tid] = 0;
  __syncthreads();
  int t = blockIdx.x * 256 + tid;
  atomicAdd(&lc[2 * eidx[2 * t]], 1);          // rank 0
  atomicAdd(&lc[2 * eidx[2 * t + 1] + 1], 1);  // rank 1
  __syncthreads();
  if (tid < 16) atomicAdd(&counts[tid], lc[tid]);
}

// ---------- fill: block-aggregated range claiming; prefix recomputed locally ----------
__global__ __launch_bounds__(256) void fill_kernel(
    const int* __restrict__ eidx, const float* __restrict__ ew,
    const int* __restrict__ counts, int* __restrict__ fill,
    int* __restrict__ rowtok, float* __restrict__ rowwt) {
  __shared__ int lc[16];
  __shared__ int lbase[16];
  __shared__ int loff[16];
  int tid = threadIdx.x;
  if (tid < 16) lc[tid] = 0;
  __syncthreads();
  int t = blockIdx.x * 256 + tid;
  int e0 = eidx[2 * t], e1 = eidx[2 * t + 1];
  int p0 = atomicAdd(&lc[2 * e0], 1);
  int p1 = atomicAdd(&lc[2 * e1 + 1], 1);
  __syncthreads();
  if (tid < 16) lbase[tid] = atomicAdd(&fill[tid], lc[tid]);
  if (tid == 64) {  // different wave than the atomics: runs concurrently
    int o = 0;
    for (int g = 0; g < 16; ++g) { loff[g] = o; o += counts[g]; }
  }
  __syncthreads();
  int pos0 = loff[2 * e0] + lbase[2 * e0] + p0;
  int pos1 = loff[2 * e1 + 1] + lbase[2 * e1 + 1] + p1;
  rowtok[pos0] = t; rowwt[pos0] = ew[2 * t];
  rowtok[pos1] = t; rowwt[pos1] = ew[2 * t + 1];
}

// ---------- per-expert transpose+convert: in [R][C] fp32 -> out [C][R] bf16 ----------
__global__ __launch_bounds__(256) void transpose_cvt(const float* __restrict__ in,
                                                     u16* __restrict__ out, int R, int C) {
  int e = blockIdx.z;
  const float* ip = in + (size_t)e * R * C;
  u16* op = out + (size_t)e * R * C;
  int c0 = blockIdx.x * 64, r0 = blockIdx.y * 64;
  __shared__ __align__(16) u16 t[64 * 68];  // [r][c], pitch 68 u16 = 136 B (8B-mult)
  int tid = threadIdx.x;
  int c4 = (tid & 15) * 4;
#pragma unroll
  for (int p = 0; p < 4; ++p) {
    int r = (tid >> 4) + 16 * p;
    float4 v = *(const float4*)(ip + (size_t)(r0 + r) * C + c0 + c4);
    uint2 pk;
    pk.x = (u32)bfc(v.x) | ((u32)bfc(v.y) << 16);
    pk.y = (u32)bfc(v.z) | ((u32)bfc(v.w) << 16);
    *(uint2*)&t[r * 68 + c4] = pk;
  }
  __syncthreads();
  int pair = tid >> 3;        // 0..31 -> output row pair (c, c+1)
  int r8 = (tid & 7) * 8;     // 8 lanes * 16B = 128B contiguous stores
  int c = 2 * pair;
  u32 u[8];
#pragma unroll
  for (int j = 0; j < 8; ++j) u[j] = *(const u32*)&t[(r8 + j) * 68 + c];
  uint4 lo, hi;
  lo.x = (u[0] & 0xffffu) | (u[1] << 16);
  lo.y = (u[2] & 0xffffu) | (u[3] << 16);
  lo.z = (u[4] & 0xffffu) | (u[5] << 16);
  lo.w = (u[6] & 0xffffu) | (u[7] << 16);
  hi.x = (u[0] >> 16) | (u[1] & 0xffff0000u);
  hi.y = (u[2] >> 16) | (u[3] & 0xffff0000u);
  hi.z = (u[4] >> 16) | (u[5] & 0xffff0000u);
  hi.w = (u[6] >> 16) | (u[7] & 0xffff0000u);
  *(uint4*)(op + (size_t)(c0 + c) * R + r0 + r8) = lo;
  *(uint4*)(op + (size_t)(c0 + c + 1) * R + r0 + r8) = hi;
}

// ---------- fc1: H[slot,f] = gelu(Xg @ W1 + b1), bf16 ----------
// R0 structure (best measured). __launch_bounds__(256,3): cap unified regs so
// 3 blocks/CU fit (76 arch + 64 acc = 140 <= 170/wave) -> +50% resident waves
// for the cross-block overlap that carries the 2-phase structure.
__global__ __launch_bounds__(256, 3) void fc1_kernel(
    const u16* __restrict__ xb, const u16* __restrict__ w1t,
    const float* __restrict__ b1, const int* __restrict__ rowtok,
    const int* __restrict__ counts, u16* __restrict__ H) {
  const int b = blockIdx.x;
  const int e = b & 7;
  const int lin = b >> 3;      // 0..2047
  const int rt = lin & 63;     // rt-fast: consecutive active blocks share B col
  const int ct = lin >> 6;     // 0..31
  int base = 0;
#pragma unroll
  for (int g = 0; g < 16; ++g) base += (g < 2 * e) ? counts[g] : 0;
  const int count = counts[2 * e] + counts[2 * e + 1];
  if (rt * 128 >= count) return;

  __shared__ __align__(16) __bf16 As[128 * 32];
  __shared__ __align__(16) __bf16 Bs[128 * 32];

  const int tid = threadIdx.x;
  const int lane = tid & 63;
  const int wave = tid >> 6;

  const int ra = tid >> 2;  // chunk row 0..63 (pass0); +64 pass1
  const int lastslot = base + count - 1;
  int s0 = base + rt * 128 + ra;       if (s0 > lastslot) s0 = lastslot;
  int s1 = base + rt * 128 + ra + 64;  if (s1 > lastslot) s1 = lastslot;
  const size_t koff = (size_t)(tid & 3) * 8;
  const u16* ga0 = xb + (size_t)rowtok[s0] * D_MODEL + koff;
  const u16* ga1 = xb + (size_t)rowtok[s1] * D_MODEL + koff;
  const u16* gb0 = w1t + (size_t)e * DIM_FF * D_MODEL + (size_t)(ct * 128 + ra) * D_MODEL + koff;
  const u16* gb1 = gb0 + (size_t)64 * D_MODEL;

  __bf16* lA0 = As + tid * 8;
  __bf16* lA1 = As + (tid + 256) * 8;
  __bf16* lB0 = Bs + tid * 8;
  __bf16* lB1 = Bs + (tid + 256) * 8;

  const int wm = (wave & 1) * 64;
  const int wn = (wave >> 1) * 64;
  const int quad = lane >> 4;
  const int lc = lane & 15;
  const __bf16* Ap = As + (wm + lc) * 32 + quad * 8;
  const __bf16* Bp = Bs + (wn + lc) * 32 + quad * 8;

  f32x4 acc[4][4];
#pragma unroll
  for (int i = 0; i < 4; ++i)
#pragma unroll
    for (int j = 0; j < 4; ++j) acc[i][j] = (f32x4)0.0f;

  for (int kt = 0; kt < D_MODEL / 32; ++kt) {
    gl2lds16(ga0 + kt * 32, lA0);
    gl2lds16(ga1 + kt * 32, lA1);
    gl2lds16(gb0 + kt * 32, lB0);
    gl2lds16(gb1 + kt * 32, lB1);
    __syncthreads();
    bf16x8 af[4], bfr[4];
#pragma unroll
    for (int mi = 0; mi < 4; ++mi) af[mi] = *(const bf16x8*)(Ap + mi * 16 * 32);
#pragma unroll
    for (int ni = 0; ni < 4; ++ni) bfr[ni] = *(const bf16x8*)(Bp + ni * 16 * 32);
#pragma unroll
    for (int mi = 0; mi < 4; ++mi)
#pragma unroll
      for (int ni = 0; ni < 4; ++ni)
        acc[mi][ni] = __builtin_amdgcn_mfma_f32_16x16x32_bf16(af[mi], bfr[ni], acc[mi][ni], 0, 0, 0);
    __syncthreads();
  }

  float bias[4];
#pragma unroll
  for (int ni = 0; ni < 4; ++ni) bias[ni] = b1[e * DIM_FF + ct * 128 + wn + ni * 16 + lc];
#pragma unroll
  for (int mi = 0; mi < 4; ++mi) {
#pragma unroll
    for (int r = 0; r < 4; ++r) {
      int m = wm + mi * 16 + quad * 4 + r;
      int grow = rt * 128 + m;
      if (grow < count) {
        size_t rowbase = (size_t)(base + grow) * DIM_FF + ct * 128 + wn;
#pragma unroll
        for (int ni = 0; ni < 4; ++ni) {
          float v = acc[mi][ni][r] + bias[ni];
          // tanh-form GELU via exp2+rcp; max abs err ~3e-4 (<< bf16 rounding of H)
          float t3 = v * (1.0f + 0.044715f * v * v);
          float u = __builtin_amdgcn_exp2f(fminf(2.302208f * t3, 80.0f));
          float h = v * u * __builtin_amdgcn_rcpf(u + 1.0f);
          H[rowbase + ni * 16 + lc] = f2bf(h);
        }
      }
    }
  }
}

// ---------- fc2 (merged single pass + K-split x2, R2's measured-293us config):
// out[tok] += wt*(H@W2 + b2) via hardware f32 atomics; out pre-zeroed.
// A token's two slots live in DIFFERENT experts -> merge is race-free.
__global__ __launch_bounds__(256, 3) void fc2_kernel(
    const u16* __restrict__ H, const u16* __restrict__ w2t,
    const float* __restrict__ b2, const int* __restrict__ rowtok,
    const float* __restrict__ rowwt, const int* __restrict__ counts,
    float* __restrict__ out) {
  const int b = blockIdx.x;
  const int e = b & 7;
  const int lin = b >> 3;      // 0..1023
  const int rt = lin & 63;     // rt-fast: B-tile reuse across neighbors
  const int ct = (lin >> 6) & 7;
  const int ks = lin >> 9;     // 0..1, K-split half
  int base = 0;
#pragma unroll
  for (int g = 0; g < 16; ++g) base += (g < 2 * e) ? counts[g] : 0;
  const int cnt = counts[2 * e] + counts[2 * e + 1];
  if (rt * 128 >= cnt) return;

  __shared__ __align__(16) __bf16 As[128 * 32];
  __shared__ __align__(16) __bf16 Bs[128 * 32];

  const int tid = threadIdx.x;
  const int lane = tid & 63;
  const int wave = tid >> 6;

  const int ra = tid >> 2;
  const size_t koff = (size_t)(tid & 3) * 8 + (size_t)ks * (DIM_FF / 2);
  const u16* ga0 = H + (size_t)(base + rt * 128 + ra) * DIM_FF + koff;  // contiguous slots
  const u16* ga1 = ga0 + (size_t)64 * DIM_FF;
  const u16* gb0 = w2t + (size_t)e * D_MODEL * DIM_FF + (size_t)(ct * 128 + ra) * DIM_FF + koff;
  const u16* gb1 = gb0 + (size_t)64 * DIM_FF;

  __bf16* lA0 = As + tid * 8;
  __bf16* lA1 = As + (tid + 256) * 8;
  __bf16* lB0 = Bs + tid * 8;
  __bf16* lB1 = Bs + (tid + 256) * 8;

  const int wm = (wave & 1) * 64;
  const int wn = (wave >> 1) * 64;
  const int quad = lane >> 4;
  const int lc = lane & 15;
  const __bf16* Ap = As + (wm + lc) * 32 + quad * 8;
  const __bf16* Bp = Bs + (wn + lc) * 32 + quad * 8;

  f32x4 acc[4][4];
#pragma unroll
  for (int i = 0; i < 4; ++i)
#pragma unroll
    for (int j = 0; j < 4; ++j) acc[i][j] = (f32x4)0.0f;

  for (int kt = 0; kt < DIM_FF / 32 / 2; ++kt) {  // 64 iters per half
    gl2lds16(ga0 + kt * 32, lA0);
    gl2lds16(ga1 + kt * 32, lA1);
    gl2lds16(gb0 + kt * 32, lB0);
    gl2lds16(gb1 + kt * 32, lB1);
    __syncthreads();
    bf16x8 af[4], bfr[4];
#pragma unroll
    for (int mi = 0; mi < 4; ++mi) af[mi] = *(const bf16x8*)(Ap + mi * 16 * 32);
#pragma unroll
    for (int ni = 0; ni < 4; ++ni) bfr[ni] = *(const bf16x8*)(Bp + ni * 16 * 32);
#pragma unroll
    for (int mi = 0; mi < 4; ++mi)
#pragma unroll
      for (int ni = 0; ni < 4; ++ni)
        acc[mi][ni] = __builtin_amdgcn_mfma_f32_16x16x32_bf16(af[mi], bfr[ni], acc[mi][ni], 0, 0, 0);
    __syncthreads();
  }

  float bias[4];
#pragma unroll
  for (int ni = 0; ni < 4; ++ni)
    bias[ni] = (ks == 0) ? b2[e * D_MODEL + ct * 128 + wn + ni * 16 + lc] : 0.0f;

#pragma unroll
  for (int mi = 0; mi < 4; ++mi) {
#pragma unroll
    for (int r = 0; r < 4; ++r) {
      int m = wm + mi * 16 + quad * 4 + r;
      int grow = rt * 128 + m;
      if (grow < cnt) {
        int slot = base + grow;
        float wt = rowwt[slot];
        float* orow = out + (size_t)rowtok[slot] * D_MODEL + ct * 128 + wn;
#pragma unroll
        for (int ni = 0; ni < 4; ++ni)
          unsafeAtomicAdd(orow + ni * 16 + lc, wt * (acc[mi][ni][r] + bias[ni]));
      }
    }
  }
}

extern "C" void kernel_launch(void* const* d_in, const int* in_sizes, int n_in,
                              void* d_out, int out_size, void* d_ws, size_t ws_size,
                              hipStream_t stream) {
  (void)in_sizes; (void)n_in; (void)ws_size; (void)out_size;
  const float* x  = (const float*)d_in[0];
  const float* Wg = (const float*)d_in[1];
  const float* bg = (const float*)d_in[2];
  const float* W1 = (const float*)d_in[3];
  const float* b1 = (const float*)d_in[4];
  const float* W2 = (const float*)d_in[5];
  const float* b2 = (const float*)d_in[6];
  float* out = (float*)d_out;

  char* ws = (char*)d_ws;
  size_t off = 0;
  int*   counts  = (int*)(ws + 0);     // 16 ints
  int*   fill    = (int*)(ws + 128);   // 16 ints
  off = 4096;
  int*   eidx    = (int*)(ws + off); off += 65536;
  float* ew      = (float*)(ws + off); off += 65536;
  int*   rowtok  = (int*)(ws + off); off += 65536;
  float* rowwt   = (float*)(ws + off); off += 65536;
  u16*   xb      = (u16*)(ws + off); off += (size_t)N_TOKENS * D_MODEL * 2;
  u16*   w1t     = (u16*)(ws + off);
  u16*   w2t     = w1t;  // ALIASED: W2 transposed after fc1 finishes reading w1t
  off += (size_t)N_EXPERTS * DIM_FF * D_MODEL * 2;
  u16*   H       = (u16*)(ws + off);
  off += (size_t)(MAX_SLOTS + 128) * DIM_FF * 2;  // +128 rows: unguarded tail reads
  // total ~216 MB

  hipMemsetAsync(ws, 0, 4096, stream);
  hipMemsetAsync(out, 0, (size_t)N_TOKENS * D_MODEL * sizeof(float), stream);  // fc2 atomics accumulate

  gate_kernel<<<N_TOKENS / 4, 256, 0, stream>>>(x, Wg, bg, eidx, ew, xb);
  count_kernel<<<N_TOKENS / 256, 256, 0, stream>>>(eidx, counts);
  fill_kernel<<<N_TOKENS / 256, 256, 0, stream>>>(eidx, ew, counts, fill, rowtok, rowwt);
  transpose_cvt<<<dim3(DIM_FF / 64, D_MODEL / 64, N_EXPERTS), 256, 0, stream>>>(W1, w1t, D_MODEL, DIM_FF);
  fc1_kernel<<<N_EXPERTS * (DIM_FF / 128) * 64, 256, 0, stream>>>(xb, w1t, b1, rowtok, counts, H);
  transpose_cvt<<<dim3(D_MODEL / 64, DIM_FF / 64, N_EXPERTS), 256, 0, stream>>>(W2, w2t, DIM_FF, D_MODEL);
  fc2_kernel<<<N_EXPERTS * (D_MODEL / 128) * 64 * 2, 256, 0, stream>>>(H, w2t, b2, rowtok, rowwt, counts, out);
}